// Round 10
// baseline (71.116 us; speedup 1.0000x reference)
//
#include <hip/hip_runtime.h>

typedef __attribute__((ext_vector_type(8))) short short8;
typedef __attribute__((ext_vector_type(4))) float f32x4;

// round-to-nearest-even f32 -> bf16 bits
__device__ __forceinline__ unsigned short f2b(float f) {
  unsigned int u = __float_as_uint(f);
  return (unsigned short)((u + 0x7FFFu + ((u >> 16) & 1u)) >> 16);
}
__device__ __forceinline__ unsigned pk2(float a, float b) {
  return (unsigned)f2b(a) | ((unsigned)f2b(b) << 16);
}

// d_out is float*, holding Re(out) only:
// Re(out)[b, i*64+k] = sum_j cos(phase[j][i])*hr[b,j*64+k] - sin(phase[j][i])*hi[b,j*64+k]
//
// R8 structure (66.75us) + operand-swapped MFMA: mfma(X, psi, acc) computes
// D[m=k][n=i] with the SAME fragments (A/B lane maps are identical for
// 16x16x32), so each acc[kt] = 4 consecutive k at fixed i -> epilogue is
// 4 nontemporal dwordx4 stores per wave instead of 16 scalar nt stores
// (kills the partial-line write amplification seen in R8: WRITE 149->131MB).
__global__ __launch_bounds__(512, 4) void tnn_kernel(
    const float* __restrict__ phase,
    const float* __restrict__ hr, const float* __restrict__ hi,
    float* __restrict__ out) {
  __shared__ alignas(16) char lds[32768];
  const int tid = threadIdx.x;
  const int lane = tid & 63;
  const int w8 = tid >> 6;
  const int b0 = blockIdx.x * 2;

  const int bb = w8 >> 2;           // batch this wave computes
  const int ibase = (w8 & 3) * 16;  // i-quarter (N=16)

  // ---- stage X into LDS: float4 loads + in-register 8jx4k transpose ----
  {
    const int p = w8 & 3;           // plane: (batch<<1)|comp
    const int jh = w8 >> 2;         // j-half
    const int jo = lane & 3;        // j-octet within half
    const int kq = lane >> 2;       // k-quad
    const float* src = (p & 1 ? hi : hr) + (size_t)(b0 + (p >> 1)) * 4096;
    const int j0 = jh * 32 + jo * 8;
    const f32x4* sp = reinterpret_cast<const f32x4*>(src + (size_t)j0 * 64 + kq * 4);
    f32x4 v[8];
#pragma unroll
    for (int q = 0; q < 8; ++q) v[q] = sp[q * 16];  // next j-row = 64 floats = 16 float4
    char* plane = lds + p * 8192;
    const int colb = jh * 64 + jo * 16;             // byte col = 2*j0
#pragma unroll
    for (int kk = 0; kk < 4; ++kk) {
      const int row = kq * 4 + kk;                  // k
      uint4 wv;
      wv.x = pk2(v[0][kk], v[1][kk]);
      wv.y = pk2(v[2][kk], v[3][kk]);
      wv.z = pk2(v[4][kk], v[5][kk]);
      wv.w = pk2(v[6][kk], v[7][kk]);
      *reinterpret_cast<uint4*>(plane + row * 128 + (colb ^ ((row & 7) << 4))) = wv;
    }
  }

  // ---- psi B-fragments in-register: Are = cos(phase[j][i]), Ans = -sin ----
  // B-frag (16x16x32): col n = i = lane&15, contraction j = (lane>>4)*8 + q.
  short8 Are[2], Ans[2];
#pragma unroll
  for (int ks = 0; ks < 2; ++ks) {
    const int i = ibase + (lane & 15);
    const int j0 = ks * 32 + (lane >> 4) * 8;
#pragma unroll
    for (int q = 0; q < 8; ++q) {
      float pph = phase[(j0 + q) * 64 + i];
      float s, c;
      __sincosf(pph, &s, &c);
      Are[ks][q] = (short)f2b(c);
      Ans[ks][q] = (short)f2b(-s);
    }
  }

  __syncthreads();

  // ---- MFMA compute (real part only), X as A-operand: D[m=k][n=i] ----
  f32x4 acc[4] = {};
  const char* Xre = lds + (bb * 2 + 0) * 8192;
  const char* Xim = lds + (bb * 2 + 1) * 8192;

#pragma unroll
  for (int kt = 0; kt < 4; ++kt) {
    const int row = kt * 16 + (lane & 15);  // k_out row in LDS tile
#pragma unroll
    for (int ks = 0; ks < 2; ++ks) {
      const int cbyte = ks * 64 + (lane >> 4) * 16;
      const int byte = row * 128 + (cbyte ^ ((row & 7) << 4));
      uint4 xr4 = *reinterpret_cast<const uint4*>(Xre + byte);
      uint4 xi4 = *reinterpret_cast<const uint4*>(Xim + byte);
      short8 xr = __builtin_bit_cast(short8, xr4);
      short8 xi = __builtin_bit_cast(short8, xi4);
      acc[kt] = __builtin_amdgcn_mfma_f32_16x16x32_bf16(xr, Are[ks], acc[kt], 0, 0, 0);
      acc[kt] = __builtin_amdgcn_mfma_f32_16x16x32_bf16(xi, Ans[ks], acc[kt], 0, 0, 0);
    }
  }

  // ---- epilogue: 4 nontemporal dwordx4 stores ----
  // D (swapped): col = i = lane&15, row = k_local = (lane>>4)*4 + r.
  // acc[kt][0..3] = out[i][kt*16 + (lane>>4)*4 .. +3] -> one float4 each.
  const size_t obase = (size_t)(b0 + bb) * 4096;
  const int i = ibase + (lane & 15);
  const int k0 = (lane >> 4) * 4;
#pragma unroll
  for (int kt = 0; kt < 4; ++kt) {
    f32x4* po = reinterpret_cast<f32x4*>(out + obase + (size_t)i * 64 + kt * 16 + k0);
    __builtin_nontemporal_store(acc[kt], po);
  }
}

extern "C" void kernel_launch(void* const* d_in, const int* in_sizes, int n_in,
                              void* d_out, int out_size, void* d_ws, size_t ws_size,
                              hipStream_t stream) {
  const float* phase = (const float*)d_in[0];
  const float* hr = (const float*)d_in[1];
  const float* hi = (const float*)d_in[2];
  float* out = (float*)d_out;

  tnn_kernel<<<4096, 512, 0, stream>>>(phase, hr, hi, out);
}

// Round 12
// 62.553 us; speedup vs baseline: 1.1369x; 1.1369x over previous
//
#include <hip/hip_runtime.h>

typedef __attribute__((ext_vector_type(8))) short short8;
typedef __attribute__((ext_vector_type(4))) float f32x4;

// round-to-nearest-even f32 -> bf16 bits
__device__ __forceinline__ unsigned short f2b(float f) {
  unsigned int u = __float_as_uint(f);
  return (unsigned short)((u + 0x7FFFu + ((u >> 16) & 1u)) >> 16);
}
__device__ __forceinline__ unsigned pk2(float a, float b) {
  return (unsigned)f2b(a) | ((unsigned)f2b(b) << 16);
}

// d_out is float*, holding Re(out) only:
// Re(out)[b, i*64+k] = sum_j cos(phase[j][i])*hr[b,j*64+k] - sin(phase[j][i])*hi[b,j*64+k]
//
// R8 structure (best: 66.75us): 512 thr = 8 waves, 2 batches, 32KB LDS,
// float4 staging + register 8jx4k transpose into XOR-swizzled [k][j] bf16
// tiles; psi (cos,-sin) in-register; nontemporal output stores.
// R11 change: epilogue transpose THROUGH LDS (R10's bpermute was wrong:
// register index depended on dest lane). After MFMA + barrier, each wave
// writes its 16x64 f32 tile to a private 4KB LDS region (scalar ds_writes,
// ^(g<<6) swizzle = conflict-free), reads back row-major (4x ds_read_b128),
// stores 4x nt dwordx4 = 1KB contiguous per instruction -> no partial lines.
// Diagnostic: WRITE_SIZE 146-149 -> ~131 MB.
__global__ __launch_bounds__(512, 4) void tnn_kernel(
    const float* __restrict__ phase,
    const float* __restrict__ hr, const float* __restrict__ hi,
    float* __restrict__ out) {
  __shared__ alignas(16) char lds[32768];
  const int tid = threadIdx.x;
  const int lane = tid & 63;
  const int w8 = tid >> 6;
  const int b0 = blockIdx.x * 2;

  const int bb = w8 >> 2;           // batch this wave computes
  const int ibase = (w8 & 3) * 16;  // i-quarter (M=16)

  // ---- stage X into LDS: float4 loads + in-register 8jx4k transpose ----
  {
    const int p = w8 & 3;           // plane: (batch<<1)|comp
    const int jh = w8 >> 2;         // j-half
    const int jo = lane & 3;        // j-octet within half
    const int kq = lane >> 2;       // k-quad
    const float* src = (p & 1 ? hi : hr) + (size_t)(b0 + (p >> 1)) * 4096;
    const int j0 = jh * 32 + jo * 8;
    const f32x4* sp = reinterpret_cast<const f32x4*>(src + (size_t)j0 * 64 + kq * 4);
    f32x4 v[8];
#pragma unroll
    for (int q = 0; q < 8; ++q) v[q] = sp[q * 16];  // next j-row = 64 floats = 16 float4
    char* plane = lds + p * 8192;
    const int colb = jh * 64 + jo * 16;             // byte col = 2*j0
#pragma unroll
    for (int kk = 0; kk < 4; ++kk) {
      const int row = kq * 4 + kk;                  // k
      uint4 wv;
      wv.x = pk2(v[0][kk], v[1][kk]);
      wv.y = pk2(v[2][kk], v[3][kk]);
      wv.z = pk2(v[4][kk], v[5][kk]);
      wv.w = pk2(v[6][kk], v[7][kk]);
      *reinterpret_cast<uint4*>(plane + row * 128 + (colb ^ ((row & 7) << 4))) = wv;
    }
  }

  // ---- psi A-fragments in-register: Are = cos(phase[j][i]), Ans = -sin ----
  // A-frag (16x16x32): row m = lane&15, k = (lane>>4)*8 + q.
  short8 Are[2], Ans[2];
#pragma unroll
  for (int ks = 0; ks < 2; ++ks) {
    const int i = ibase + (lane & 15);
    const int j0 = ks * 32 + (lane >> 4) * 8;
#pragma unroll
    for (int q = 0; q < 8; ++q) {
      float pph = phase[(j0 + q) * 64 + i];
      float s, c;
      __sincosf(pph, &s, &c);
      Are[ks][q] = (short)f2b(c);
      Ans[ks][q] = (short)f2b(-s);
    }
  }

  __syncthreads();

  // ---- MFMA compute (real part only) ----
  f32x4 acc[4] = {};
  const char* Xre = lds + (bb * 2 + 0) * 8192;
  const char* Xim = lds + (bb * 2 + 1) * 8192;

#pragma unroll
  for (int kt = 0; kt < 4; ++kt) {
    const int row = kt * 16 + (lane & 15);
#pragma unroll
    for (int ks = 0; ks < 2; ++ks) {
      const int cbyte = ks * 64 + (lane >> 4) * 16;
      const int byte = row * 128 + (cbyte ^ ((row & 7) << 4));
      uint4 xr4 = *reinterpret_cast<const uint4*>(Xre + byte);
      uint4 xi4 = *reinterpret_cast<const uint4*>(Xim + byte);
      short8 xr = __builtin_bit_cast(short8, xr4);
      short8 xi = __builtin_bit_cast(short8, xi4);
      acc[kt] = __builtin_amdgcn_mfma_f32_16x16x32_bf16(Are[ks], xr, acc[kt], 0, 0, 0);
      acc[kt] = __builtin_amdgcn_mfma_f32_16x16x32_bf16(Ans[ks], xi, acc[kt], 0, 0, 0);
    }
  }

  // ---- epilogue: transpose via per-wave 4KB LDS tile, full-line nt stores ----
  // acc: lane (g=lane>>4, c=lane&15) holds (i = ibase+g*4+r, k = kt*16+c)
  // in acc[kt][r]. LDS tile: [16 rows i][64 cols k] f32, rows 256B,
  // col-byte swizzle ^(g<<6) where g = row>>2 (write: 2 lanes/bank = free).
  __syncthreads();  // all waves done reading X planes; reuse all 32KB
  char* et = lds + w8 * 4096;
  {
    const int g = lane >> 4, c = lane & 15;
#pragma unroll
    for (int kt = 0; kt < 4; ++kt) {
#pragma unroll
      for (int r = 0; r < 4; ++r) {
        const int row = g * 4 + r;
        const int cb = (kt * 16 + c) * 4;
        *reinterpret_cast<float*>(et + row * 256 + (cb ^ (g << 6))) = acc[kt][r];
      }
    }
  }
  // intra-wave LDS RAW: DS pipe is in-order per wave; enforce compiler order
  asm volatile("s_waitcnt lgkmcnt(0)" ::: "memory");

  // read back row-major: instruction rr covers rows rr*4..rr*4+3 (h=lane>>4),
  // 16 lanes x 16B per row; store = 1KB contiguous nt dwordx4 per wave.
  const size_t obase = (size_t)(b0 + bb) * 4096 + (size_t)ibase * 64;
  const int h = lane >> 4, c = lane & 15;
#pragma unroll
  for (int rr = 0; rr < 4; ++rr) {
    const int row = rr * 4 + h;
    const int cb = c * 16;
    f32x4 v = *reinterpret_cast<const f32x4*>(et + row * 256 + (cb ^ ((row >> 2) << 6)));
    __builtin_nontemporal_store(
        v, reinterpret_cast<f32x4*>(out + obase + (size_t)row * 64 + c * 4));
  }
}

extern "C" void kernel_launch(void* const* d_in, const int* in_sizes, int n_in,
                              void* d_out, int out_size, void* d_ws, size_t ws_size,
                              hipStream_t stream) {
  const float* phase = (const float*)d_in[0];
  const float* hr = (const float*)d_in[1];
  const float* hi = (const float*)d_in[2];
  float* out = (float*)d_out;

  tnn_kernel<<<4096, 512, 0, stream>>>(phase, hr, hi, out);
}

// Round 14
// 62.424 us; speedup vs baseline: 1.1392x; 1.0021x over previous
//
#include <hip/hip_runtime.h>

typedef __attribute__((ext_vector_type(8))) short short8;
typedef __attribute__((ext_vector_type(4))) float f32x4;

// round-to-nearest-even f32 -> bf16 bits
__device__ __forceinline__ unsigned short f2b(float f) {
  unsigned int u = __float_as_uint(f);
  return (unsigned short)((u + 0x7FFFu + ((u >> 16) & 1u)) >> 16);
}
__device__ __forceinline__ unsigned pk2(float a, float b) {
  return (unsigned)f2b(a) | ((unsigned)f2b(b) << 16);
}

// d_out is float*, holding Re(out) only:
// Re(out)[b, i*64+k] = sum_j cos(phase[j][i])*hr[b,j*64+k] - sin(phase[j][i])*hi[b,j*64+k]
//
// R11 final structure (62.55us, minimal WRITE=131MB):
//  - 512 thr = 8 waves, 2 batches/block, 32KB LDS, grid 4096
//  - float4 staging loads + register 8jx4k transpose into XOR-swizzled
//    [k=64][j=64] bf16 tiles (conflict-free writes and reads)
//  - psi (cos,-sin) fragments in-register from phase (L2-resident, 16KB)
//  - bf16 MFMA 16x16x32, fp32 accum (absmax 0.25 vs 0.88 threshold)
//  - epilogue transpose through per-wave 4KB LDS tile -> each nt store
//    writes 1KB contiguous (full 128B lines only; kills the 14% write
//    amplification that scalar/columned nt stores showed in R8/R9)
// NOTE: nt-only stores (__builtin_nontemporal_store). Do NOT use sc1
// system-scope stores here — the harness primes d_out via hipMemsetAsync
// through the normal cache path; sc1 bypass loses those lines (R12 failure).
__global__ __launch_bounds__(512, 4) void tnn_kernel(
    const float* __restrict__ phase,
    const float* __restrict__ hr, const float* __restrict__ hi,
    float* __restrict__ out) {
  __shared__ alignas(16) char lds[32768];
  const int tid = threadIdx.x;
  const int lane = tid & 63;
  const int w8 = tid >> 6;
  const int b0 = blockIdx.x * 2;

  const int bb = w8 >> 2;           // batch this wave computes
  const int ibase = (w8 & 3) * 16;  // i-quarter (M=16)

  // ---- stage X into LDS: float4 loads + in-register 8jx4k transpose ----
  {
    const int p = w8 & 3;           // plane: (batch<<1)|comp
    const int jh = w8 >> 2;         // j-half
    const int jo = lane & 3;        // j-octet within half
    const int kq = lane >> 2;       // k-quad
    const float* src = (p & 1 ? hi : hr) + (size_t)(b0 + (p >> 1)) * 4096;
    const int j0 = jh * 32 + jo * 8;
    const f32x4* sp = reinterpret_cast<const f32x4*>(src + (size_t)j0 * 64 + kq * 4);
    f32x4 v[8];
#pragma unroll
    for (int q = 0; q < 8; ++q) v[q] = sp[q * 16];  // next j-row = 64 floats = 16 float4
    char* plane = lds + p * 8192;
    const int colb = jh * 64 + jo * 16;             // byte col = 2*j0
#pragma unroll
    for (int kk = 0; kk < 4; ++kk) {
      const int row = kq * 4 + kk;                  // k
      uint4 wv;
      wv.x = pk2(v[0][kk], v[1][kk]);
      wv.y = pk2(v[2][kk], v[3][kk]);
      wv.z = pk2(v[4][kk], v[5][kk]);
      wv.w = pk2(v[6][kk], v[7][kk]);
      *reinterpret_cast<uint4*>(plane + row * 128 + (colb ^ ((row & 7) << 4))) = wv;
    }
  }

  // ---- psi A-fragments in-register: Are = cos(phase[j][i]), Ans = -sin ----
  // A-frag (16x16x32): row m = lane&15, k = (lane>>4)*8 + q.
  short8 Are[2], Ans[2];
#pragma unroll
  for (int ks = 0; ks < 2; ++ks) {
    const int i = ibase + (lane & 15);
    const int j0 = ks * 32 + (lane >> 4) * 8;
#pragma unroll
    for (int q = 0; q < 8; ++q) {
      float pph = phase[(j0 + q) * 64 + i];
      float s, c;
      __sincosf(pph, &s, &c);
      Are[ks][q] = (short)f2b(c);
      Ans[ks][q] = (short)f2b(-s);
    }
  }

  __syncthreads();

  // ---- MFMA compute (real part only) ----
  f32x4 acc[4] = {};
  const char* Xre = lds + (bb * 2 + 0) * 8192;
  const char* Xim = lds + (bb * 2 + 1) * 8192;

#pragma unroll
  for (int kt = 0; kt < 4; ++kt) {
    const int row = kt * 16 + (lane & 15);
#pragma unroll
    for (int ks = 0; ks < 2; ++ks) {
      const int cbyte = ks * 64 + (lane >> 4) * 16;
      const int byte = row * 128 + (cbyte ^ ((row & 7) << 4));
      uint4 xr4 = *reinterpret_cast<const uint4*>(Xre + byte);
      uint4 xi4 = *reinterpret_cast<const uint4*>(Xim + byte);
      short8 xr = __builtin_bit_cast(short8, xr4);
      short8 xi = __builtin_bit_cast(short8, xi4);
      acc[kt] = __builtin_amdgcn_mfma_f32_16x16x32_bf16(Are[ks], xr, acc[kt], 0, 0, 0);
      acc[kt] = __builtin_amdgcn_mfma_f32_16x16x32_bf16(Ans[ks], xi, acc[kt], 0, 0, 0);
    }
  }

  // ---- epilogue: transpose via per-wave 4KB LDS tile, full-line nt stores ----
  // acc: lane (g=lane>>4, c=lane&15) holds (i = ibase+g*4+r, k = kt*16+c)
  // in acc[kt][r]. LDS tile: [16 rows i][64 cols k] f32, rows 256B,
  // col-byte swizzle ^(g<<6) where g = row>>2 (write: 2 lanes/bank = free).
  __syncthreads();  // all waves done reading X planes; reuse all 32KB
  char* et = lds + w8 * 4096;
  {
    const int g = lane >> 4, c = lane & 15;
#pragma unroll
    for (int kt = 0; kt < 4; ++kt) {
#pragma unroll
      for (int r = 0; r < 4; ++r) {
        const int row = g * 4 + r;
        const int cb = (kt * 16 + c) * 4;
        *reinterpret_cast<float*>(et + row * 256 + (cb ^ (g << 6))) = acc[kt][r];
      }
    }
  }
  // intra-wave LDS RAW: DS pipe is in-order per wave; enforce compiler order
  asm volatile("s_waitcnt lgkmcnt(0)" ::: "memory");

  // read back row-major: instruction rr covers rows rr*4..rr*4+3 (h=lane>>4),
  // 16 lanes x 16B per row; store = 1KB contiguous nt dwordx4 per wave.
  const size_t obase = (size_t)(b0 + bb) * 4096 + (size_t)ibase * 64;
  const int h = lane >> 4, c = lane & 15;
#pragma unroll
  for (int rr = 0; rr < 4; ++rr) {
    const int row = rr * 4 + h;
    const int cb = c * 16;
    f32x4 v = *reinterpret_cast<const f32x4*>(et + row * 256 + (cb ^ ((row >> 2) << 6)));
    __builtin_nontemporal_store(
        v, reinterpret_cast<f32x4*>(out + obase + (size_t)row * 64 + c * 4));
  }
}

extern "C" void kernel_launch(void* const* d_in, const int* in_sizes, int n_in,
                              void* d_out, int out_size, void* d_ws, size_t ws_size,
                              hipStream_t stream) {
  const float* phase = (const float*)d_in[0];
  const float* hr = (const float*)d_in[1];
  const float* hi = (const float*)d_in[2];
  float* out = (float*)d_out;

  tnn_kernel<<<4096, 512, 0, stream>>>(phase, hr, hi, out);
}